// Round 8
// baseline (1259.450 us; speedup 1.0000x reference)
//
#include <hip/hip_runtime.h>
#include <hip/hip_fp16.h>

#define HID 64

struct alignas(8)  H4 { __half2 a, b; };
struct alignas(16) H8 { __half2 h[4]; };

typedef _Float16 h2n __attribute__((ext_vector_type(2)));

__device__ inline float dot2f(__half2 a, __half2 b, float c) {
#if __has_builtin(__builtin_amdgcn_fdot2)
    h2n an, bn;
    __builtin_memcpy(&an, &a, 4);
    __builtin_memcpy(&bn, &b, 4);
    return __builtin_amdgcn_fdot2(an, bn, c, false);
#else
    float2 af = __half22float2(a), bf = __half22float2(b);
    return c + af.x * bf.x + af.y * bf.y;
#endif
}

// ===========================================================================
// CSR build: histogram + scan + permutation (+ fp16 edge-feature reorder)
// ===========================================================================
__global__ __launch_bounds__(256) void deg_count(const int* __restrict__ dst,
                                                 int* __restrict__ deg, int E) {
    int e = blockIdx.x * 256 + threadIdx.x;
    if (e < E) atomicAdd(&deg[dst[e]], 1);
}

__global__ __launch_bounds__(256) void scan1(const int* __restrict__ deg,
                                             int* __restrict__ rowptr,
                                             int* __restrict__ bsums, int N) {
    __shared__ int s[256];
    const int t = threadIdx.x;
    const int base = blockIdx.x * 2048 + t * 8;
    int v[8], tot = 0;
    #pragma unroll
    for (int i = 0; i < 8; i++) {
        int x = (base + i < N) ? deg[base + i] : 0;
        v[i] = tot; tot += x;
    }
    s[t] = tot; __syncthreads();
    for (int off = 1; off < 256; off <<= 1) {
        int a = (t >= off) ? s[t - off] : 0;
        __syncthreads(); s[t] += a; __syncthreads();
    }
    const int texcl = s[t] - tot;
    #pragma unroll
    for (int i = 0; i < 8; i++)
        if (base + i < N) rowptr[base + i] = texcl + v[i];
    if (t == 255) bsums[blockIdx.x] = s[255];
}

__global__ void scan2(int* bsums, int NB) {
    if (blockIdx.x == 0 && threadIdx.x == 0) {
        int run = 0;
        for (int i = 0; i < NB; i++) { int x = bsums[i]; bsums[i] = run; run += x; }
    }
}

__global__ __launch_bounds__(256) void scan3(int* __restrict__ rowptr,
                                             const int* __restrict__ bsums,
                                             int N, int E) {
    int idx = blockIdx.x * 256 + threadIdx.x;
    if (idx < N) rowptr[idx] += bsums[idx >> 11];
    if (idx == 0) rowptr[N] = E;
}

__global__ __launch_bounds__(256) void permute_k(
    const int* __restrict__ src, const int* __restrict__ dst,
    const int* __restrict__ rowptr, int* __restrict__ cursor,
    const float* __restrict__ Xe, __half* __restrict__ Xes,
    unsigned* __restrict__ pks, int E)
{
    int e = blockIdx.x * 256 + threadIdx.x;
    if (e >= E) return;
    int d = dst[e];
    int pos = rowptr[d] + atomicAdd(&cursor[d], 1);
    pks[pos] = ((unsigned)src[e] << 5) | (unsigned)(d & 31);
    const float4* xi = (const float4*)&Xe[(size_t)e * 16];
    float4 x0 = xi[0], x1 = xi[1], x2 = xi[2], x3 = xi[3];
    H8 h0, h1;
    h0.h[0] = __float22half2_rn(make_float2(x0.x, x0.y));
    h0.h[1] = __float22half2_rn(make_float2(x0.z, x0.w));
    h0.h[2] = __float22half2_rn(make_float2(x1.x, x1.y));
    h0.h[3] = __float22half2_rn(make_float2(x1.z, x1.w));
    h1.h[0] = __float22half2_rn(make_float2(x2.x, x2.y));
    h1.h[1] = __float22half2_rn(make_float2(x2.z, x2.w));
    h1.h[2] = __float22half2_rn(make_float2(x3.x, x3.y));
    h1.h[3] = __float22half2_rn(make_float2(x3.z, x3.w));
    H8* xo = (H8*)&Xes[(size_t)pos * 16];
    xo[0] = h0; xo[1] = h1;
}

// ===========================================================================
// pm_dual: PMh[n] = fp16(h@Wm_top + bm), Th[n] = fp16(h@Wu_top + bu)
// (only used for layer 0; hidden-layer PM/Th are fused into edge_fused)
// ===========================================================================
template<int K1>
__global__ __launch_bounds__(256) void pm_dual(
    const float* __restrict__ Hn,
    const float* __restrict__ Wm, const float* __restrict__ bm,
    const float* __restrict__ Wu, const float* __restrict__ bu,
    __half* __restrict__ PMh, __half* __restrict__ Th, int N)
{
    constexpr int KP = K1 + 4;
    constexpr int P4 = K1 / 4;
    __shared__ float Ws[K1 * 128];
    __shared__ float Xs[32 * KP];

    const int tid = threadIdx.x;
    for (int i = tid; i < K1 * 32; i += 256) {
        const int row = i >> 5, c4 = i & 31;
        float4 v = (c4 < 16) ? *(const float4*)&Wm[row * 64 + c4 * 4]
                             : *(const float4*)&Wu[row * 64 + (c4 - 16) * 4];
        *(float4*)&Ws[row * 128 + c4 * 4] = v;
    }
    const int nbase = blockIdx.x * 32;
    for (int i = tid; i < 32 * P4; i += 256) {
        const int nl = i / P4, part = i % P4;
        const int n = nbase + nl;
        if (n < N)
            *(float4*)&Xs[nl * KP + part * 4] =
                *(const float4*)&Hn[(size_t)n * K1 + part * 4];
    }
    __syncthreads();

    const int c0 = (tid & 31) * 4;
    const int n0 = (tid >> 5) * 4;
    const float4 bv = (c0 < 64) ? *(const float4*)&bm[c0]
                                : *(const float4*)&bu[c0 - 64];

    float4 acc[4];
    #pragma unroll
    for (int i = 0; i < 4; i++) acc[i] = bv;

    #pragma unroll 4
    for (int k = 0; k < K1; k += 4) {
        const float4 w0 = *(const float4*)&Ws[(k + 0) * 128 + c0];
        const float4 w1 = *(const float4*)&Ws[(k + 1) * 128 + c0];
        const float4 w2 = *(const float4*)&Ws[(k + 2) * 128 + c0];
        const float4 w3 = *(const float4*)&Ws[(k + 3) * 128 + c0];
        #pragma unroll
        for (int ni = 0; ni < 4; ni++) {
            const float4 xv = *(const float4*)&Xs[(n0 + ni) * KP + k];
            acc[ni].x += xv.x * w0.x + xv.y * w1.x + xv.z * w2.x + xv.w * w3.x;
            acc[ni].y += xv.x * w0.y + xv.y * w1.y + xv.z * w2.y + xv.w * w3.y;
            acc[ni].z += xv.x * w0.z + xv.y * w1.z + xv.z * w2.z + xv.w * w3.z;
            acc[ni].w += xv.x * w0.w + xv.y * w1.w + xv.z * w2.w + xv.w * w3.w;
        }
    }

    #pragma unroll
    for (int ni = 0; ni < 4; ni++) {
        const int n = nbase + n0 + ni;
        if (n < N) {
            H4 o;
            o.a = __float22half2_rn(make_float2(acc[ni].x, acc[ni].y));
            o.b = __float22half2_rn(make_float2(acc[ni].z, acc[ni].w));
            if (c0 < 64) *(H4*)&PMh[(size_t)n * 64 + c0]      = o;
            else         *(H4*)&Th [(size_t)n * 64 + c0 - 64] = o;
        }
    }
}

// ===========================================================================
// edge_fused v6: R7 semantics, VGPR-dieted to the <=64 tier (launch_bounds
// (256,8) => 8 blocks/CU cap, 32 waves/CU vs 16 at 84 VGPR).
//  - Xes register double-buffer (32 VGPR) -> per-wave LDS double buffer,
//    stride 48B/edge (2-way bank conflicts = free; group reads broadcast).
//    Stage load 8B/lane coalesced, 1 chunk ahead; ds_write after compute.
//  - PM gathers stay 1-ahead; phA/phB alternate via unroll-2 (no rotate movs).
//  - Scatter local-dst packed into 1 ldp scalar at gather time (pk 12->8).
//  - FUSE epilogue in two 2-node passes to cap register peak.
// ===========================================================================
template<bool FUSE>
__global__ __launch_bounds__(256, 8) void edge_fused(
    const __half*   __restrict__ PMh,   // [N, 64]
    const __half*   __restrict__ Th,    // [N, 64]
    const __half*   __restrict__ Xes,   // [E, 16] dst-sorted
    const unsigned* __restrict__ pks,   // [E] (src<<5)|ld
    const int*      __restrict__ rowptr,
    const float*    __restrict__ Mwb,   // [16, 64] message bottom
    const float*    __restrict__ Uwb,   // [64, 64] update bottom
    const float*    __restrict__ MwN,   // [64, 64] next-layer M top (FUSE)
    const float*    __restrict__ MbN,
    const float*    __restrict__ UwN,   // [64, 64] next-layer U top (FUSE)
    const float*    __restrict__ UbN,
    __half*         __restrict__ PMo,   // [N, 64] out (FUSE)
    __half*         __restrict__ Tho,   // [N, 64] out (FUSE)
    float*          __restrict__ Yout,  // [N, 64] out (!FUSE, final layer)
    int N)
{
    constexpr int AGP  = HID + 4;
    constexpr int SLOT = 48;                 // bytes per staged edge record
    __shared__ float aggs[32 * AGP];         // 8704 B
    __shared__ char  xsh[4][2][16 * SLOT];   // 6144 B per-wave dbuf

    const int tid  = threadIdx.x;
    const int wv   = tid >> 6;
    const int lane = tid & 63;
    const int c0   = (lane & 15) * 4;
    const int g    = lane >> 4;
    const int laneE = lane >> 2;             // edge this lane stages (0..15)
    const int laneP = (lane & 3) * 8;        // byte part of the 32B record

    // dot2 weight pairs: wh[p][j] = (Mwb[2p][c0+j], Mwb[2p+1][c0+j])
    __half2 wh[8][4];
    #pragma unroll
    for (int p = 0; p < 8; p++)
        #pragma unroll
        for (int j = 0; j < 4; j++)
            wh[p][j] = __float22half2_rn(make_float2(Mwb[(2 * p) * 64 + c0 + j],
                                                     Mwb[(2 * p + 1) * 64 + c0 + j]));

    for (int i = tid; i < 32 * AGP; i += 256) aggs[i] = 0.f;

    const int nbase  = blockIdx.x * 32;
    const int nend   = (nbase + 32 < N) ? nbase + 32 : N;
    const int estart = rowptr[nbase];
    const int eend   = rowptr[nend];
    __syncthreads();

    const int pc0 = estart + wv * 16;

    unsigned pk0[4], pk1[4];     // pk regs: chunks i+1 / i+2 alternating
    H4       phA[4], phB[4];     // PM gathers, alternate by parity
    unsigned ldpA = 0, ldpB = 0; // packed local-dst (8-bit fields)
    uint2    xt;                 // staged 8B of Xes (load ... ds_write)

    // GATH: issue PM gathers for the next chunk from PKB, pack ldp, then
    // refill PKB with the pks of chunk (PCN).
#define GATH(PKB, PHB, LDPB, PCN) do {                                        \
    unsigned l_ = 0;                                                          \
    _Pragma("unroll")                                                         \
    for (int s = 0; s < 4; s++) {                                             \
        const unsigned pk_ = PKB[s];                                          \
        PHB[s] = *(const H4*)&PMh[(size_t)(pk_ >> 5) * 64 + c0];              \
        l_ |= (pk_ & 31u) << (8 * s);                                         \
    }                                                                         \
    LDPB = l_;                                                                \
    _Pragma("unroll")                                                         \
    for (int s = 0; s < 4; s++) {                                             \
        const int pe_ = (PCN) + g * 4 + s;                                    \
        PKB[s] = pks[pe_ < eend ? pe_ : eend - 1];                            \
    }                                                                         \
} while (0)

#define LOADX(CB) do {                                                        \
    const int pe_  = (CB) + laneE;                                            \
    const int pcl_ = pe_ < eend ? pe_ : eend - 1;                             \
    xt = *(const uint2*)((const char*)Xes + (size_t)pcl_ * 32 + laneP);       \
} while (0)

#define WRITEX(BUF)                                                           \
    *(uint2*)&xsh[wv][BUF][laneE * SLOT + laneP] = xt

#define COMPUTE(BUF, PH, LDP, PCC) do {                                       \
    int ld_prev = -1;                                                         \
    float4 racc = make_float4(0.f, 0.f, 0.f, 0.f);                            \
    _Pragma("unroll")                                                         \
    for (int s = 0; s < 4; s++) {                                             \
        const int e_ = g * 4 + s;                                             \
        const H8 x0 = *(const H8*)&xsh[wv][BUF][e_ * SLOT];                   \
        const H8 x1 = *(const H8*)&xsh[wv][BUF][e_ * SLOT + 16];              \
        const float2 pl = __half22float2(PH[s].a);                            \
        const float2 pu = __half22float2(PH[s].b);                            \
        float a0 = pl.x, a1 = pl.y, a2 = pu.x, a3 = pu.y;                     \
        _Pragma("unroll")                                                     \
        for (int p = 0; p < 4; p++) {                                         \
            const __half2 xv = x0.h[p];                                       \
            a0 = dot2f(xv, wh[p][0], a0); a1 = dot2f(xv, wh[p][1], a1);       \
            a2 = dot2f(xv, wh[p][2], a2); a3 = dot2f(xv, wh[p][3], a3);       \
        }                                                                     \
        _Pragma("unroll")                                                     \
        for (int p = 0; p < 4; p++) {                                         \
            const __half2 xv = x1.h[p];                                       \
            a0 = dot2f(xv, wh[p+4][0], a0); a1 = dot2f(xv, wh[p+4][1], a1);   \
            a2 = dot2f(xv, wh[p+4][2], a2); a3 = dot2f(xv, wh[p+4][3], a3);   \
        }                                                                     \
        float4 v;                                                             \
        v.x = fmaxf(a0, 0.f); v.y = fmaxf(a1, 0.f);                           \
        v.z = fmaxf(a2, 0.f); v.w = fmaxf(a3, 0.f);                           \
        const int ld = ((PCC) + e_ < eend)                                    \
                     ? (int)((LDP >> (8 * s)) & 31u) : -1;                    \
        if (ld == ld_prev) {                                                  \
            racc.x += v.x; racc.y += v.y; racc.z += v.z; racc.w += v.w;       \
        } else {                                                              \
            if (ld_prev >= 0) {                                               \
                float* a_ = &aggs[ld_prev * AGP + c0];                        \
                atomicAdd(a_ + 0, racc.x); atomicAdd(a_ + 1, racc.y);         \
                atomicAdd(a_ + 2, racc.z); atomicAdd(a_ + 3, racc.w);         \
            }                                                                 \
            racc = v; ld_prev = ld;                                           \
        }                                                                     \
    }                                                                         \
    if (ld_prev >= 0) {                                                       \
        float* a_ = &aggs[ld_prev * AGP + c0];                                \
        atomicAdd(a_ + 0, racc.x); atomicAdd(a_ + 1, racc.y);                 \
        atomicAdd(a_ + 2, racc.z); atomicAdd(a_ + 3, racc.w);                 \
    }                                                                         \
} while (0)

    if (pc0 < eend) {
        // prologue: chunk0 pks -> gathers (phA) ; pk0 <- chunk1, pk1 <- chunk2;
        // stage chunk0 into LDS buf0.
        {
            unsigned l_ = 0;
            #pragma unroll
            for (int s = 0; s < 4; s++) {
                const int pe = pc0 + g * 4 + s;
                const unsigned pkc = pks[pe < eend ? pe : eend - 1];
                phA[s] = *(const H4*)&PMh[(size_t)(pkc >> 5) * 64 + c0];
                l_ |= (pkc & 31u) << (8 * s);
            }
            ldpA = l_;
            #pragma unroll
            for (int s = 0; s < 4; s++) {
                int pe = pc0 + 64 + g * 4 + s;
                pk0[s] = pks[pe < eend ? pe : eend - 1];
                pe = pc0 + 128 + g * 4 + s;
                pk1[s] = pks[pe < eend ? pe : eend - 1];
            }
            LOADX(pc0);
            WRITEX(0);
        }

        // unroll-2 steady state: iter computing chunk i (buf i&1):
        //   LOADX chunk i+1 ; GATH chunk i+1 (other ph), refill pk <- i+3 ;
        //   COMPUTE chunk i ; WRITEX chunk i+1 into other buf.
        int pc = pc0;
        while (true) {
            { LOADX(pc + 64); GATH(pk0, phB, ldpB, pc + 192);
              COMPUTE(0, phA, ldpA, pc); WRITEX(1); }
            pc += 64; if (pc >= eend) break;
            { LOADX(pc + 64); GATH(pk1, phA, ldpA, pc + 192);
              COMPUTE(1, phB, ldpB, pc); WRITEX(0); }
            pc += 64; if (pc >= eend) break;
        }
    }

#undef GATH
#undef LOADX
#undef WRITEX
#undef COMPUTE

    __syncthreads();

    // ---- fused node update: y = relu(T + aggs @ Uw_bot), Uwb via L1 ----
    const int c0t = (tid & 15) * 4;
    const int r0  = tid >> 4;
    const int r1  = r0 + 16;
    const int n0g = nbase + r0, n1g = nbase + r1;
    float4 acc0 = make_float4(0.f, 0.f, 0.f, 0.f);
    float4 acc1 = make_float4(0.f, 0.f, 0.f, 0.f);
    if (n0g < N) {
        H4 th = *(const H4*)&Th[(size_t)n0g * 64 + c0t];
        float2 lo = __half22float2(th.a), hi = __half22float2(th.b);
        acc0 = make_float4(lo.x, lo.y, hi.x, hi.y);
    }
    if (n1g < N) {
        H4 th = *(const H4*)&Th[(size_t)n1g * 64 + c0t];
        float2 lo = __half22float2(th.a), hi = __half22float2(th.b);
        acc1 = make_float4(lo.x, lo.y, hi.x, hi.y);
    }
    #pragma unroll 4
    for (int k = 0; k < 64; k += 4) {
        const float4 w0 = *(const float4*)&Uwb[(k + 0) * 64 + c0t];
        const float4 w1 = *(const float4*)&Uwb[(k + 1) * 64 + c0t];
        const float4 w2 = *(const float4*)&Uwb[(k + 2) * 64 + c0t];
        const float4 w3 = *(const float4*)&Uwb[(k + 3) * 64 + c0t];
        const float4 x0 = *(const float4*)&aggs[r0 * AGP + k];
        const float4 x1 = *(const float4*)&aggs[r1 * AGP + k];
        acc0.x += x0.x * w0.x + x0.y * w1.x + x0.z * w2.x + x0.w * w3.x;
        acc0.y += x0.x * w0.y + x0.y * w1.y + x0.z * w2.y + x0.w * w3.y;
        acc0.z += x0.x * w0.z + x0.y * w1.z + x0.z * w2.z + x0.w * w3.z;
        acc0.w += x0.x * w0.w + x0.y * w1.w + x0.z * w2.w + x0.w * w3.w;
        acc1.x += x1.x * w0.x + x1.y * w1.x + x1.z * w2.x + x1.w * w3.x;
        acc1.y += x1.x * w0.y + x1.y * w1.y + x1.z * w2.y + x1.w * w3.y;
        acc1.z += x1.x * w0.z + x1.y * w1.z + x1.z * w2.z + x1.w * w3.z;
        acc1.w += x1.x * w0.w + x1.y * w1.w + x1.z * w2.w + x1.w * w3.w;
    }
    float4 y0, y1;
    y0.x = fmaxf(acc0.x, 0.f); y0.y = fmaxf(acc0.y, 0.f);
    y0.z = fmaxf(acc0.z, 0.f); y0.w = fmaxf(acc0.w, 0.f);
    y1.x = fmaxf(acc1.x, 0.f); y1.y = fmaxf(acc1.y, 0.f);
    y1.z = fmaxf(acc1.z, 0.f); y1.w = fmaxf(acc1.w, 0.f);

    if (!FUSE) {
        if (n0g < N) *(float4*)&Yout[(size_t)n0g * HID + c0t] = y0;
        if (n1g < N) *(float4*)&Yout[(size_t)n1g * HID + c0t] = y1;
    } else {
        // ---- in-block pm for NEXT layer: PM/Th = fp16(y@W_top + b) ----
        __syncthreads();                       // all aggs reads done
        *(float4*)&aggs[r0 * AGP + c0t] = y0;  // stage y in aggs
        *(float4*)&aggs[r1 * AGP + c0t] = y1;
        __syncthreads();

        const int c2  = (tid & 31) * 4;        // 0..124 (128 out cols)
        const int nn0 = (tid >> 5) * 4;        // 4 nodes/thread
        const bool isM = (c2 < 64);
        const float* Wn = isM ? MwN : UwN;
        const float* bn = isM ? MbN : UbN;
        const int cc = isM ? c2 : c2 - 64;
        const float4 bv = *(const float4*)&bn[cc];

        #pragma unroll 1
        for (int h = 0; h < 2; h++) {          // two 2-node passes (reg cap)
            const int na = nn0 + 2 * h, nb = na + 1;
            float4 p0 = bv, p1 = bv;
            #pragma unroll 4
            for (int k = 0; k < 64; k += 4) {
                const float4 w0 = *(const float4*)&Wn[(k + 0) * 64 + cc];
                const float4 w1 = *(const float4*)&Wn[(k + 1) * 64 + cc];
                const float4 w2 = *(const float4*)&Wn[(k + 2) * 64 + cc];
                const float4 w3 = *(const float4*)&Wn[(k + 3) * 64 + cc];
                const float4 x0 = *(const float4*)&aggs[na * AGP + k];
                const float4 x1 = *(const float4*)&aggs[nb * AGP + k];
                p0.x += x0.x * w0.x + x0.y * w1.x + x0.z * w2.x + x0.w * w3.x;
                p0.y += x0.x * w0.y + x0.y * w1.y + x0.z * w2.y + x0.w * w3.y;
                p0.z += x0.x * w0.z + x0.y * w1.z + x0.z * w2.z + x0.w * w3.z;
                p0.w += x0.x * w0.w + x0.y * w1.w + x0.z * w2.w + x0.w * w3.w;
                p1.x += x1.x * w0.x + x1.y * w1.x + x1.z * w2.x + x1.w * w3.x;
                p1.y += x1.x * w0.y + x1.y * w1.y + x1.z * w2.y + x1.w * w3.y;
                p1.z += x1.x * w0.z + x1.y * w1.z + x1.z * w2.z + x1.w * w3.z;
                p1.w += x1.x * w0.w + x1.y * w1.w + x1.z * w2.w + x1.w * w3.w;
            }
            if (nbase + na < N) {
                H4 o;
                o.a = __float22half2_rn(make_float2(p0.x, p0.y));
                o.b = __float22half2_rn(make_float2(p0.z, p0.w));
                if (isM) *(H4*)&PMo[(size_t)(nbase + na) * 64 + cc] = o;
                else     *(H4*)&Tho[(size_t)(nbase + na) * 64 + cc] = o;
            }
            if (nbase + nb < N) {
                H4 o;
                o.a = __float22half2_rn(make_float2(p1.x, p1.y));
                o.b = __float22half2_rn(make_float2(p1.z, p1.w));
                if (isM) *(H4*)&PMo[(size_t)(nbase + nb) * 64 + cc] = o;
                else     *(H4*)&Tho[(size_t)(nbase + nb) * 64 + cc] = o;
            }
        }
    }
}

// ===========================================================================
// pool_head: out[g] = (sum_{n in graph g} y[n]) . Ww + Wb  (sorted batch_idx)
// ===========================================================================
__global__ __launch_bounds__(256) void pool_head(
    const float* __restrict__ Y, const int* __restrict__ bidx,
    const float* __restrict__ Ww, const float* __restrict__ Wb,
    float* __restrict__ out, int N)
{
    const int g = blockIdx.x;
    int a = 0, b = N;
    while (a < b) { int m = (a + b) >> 1; if (bidx[m] < g) a = m + 1; else b = m; }
    const int lo = a;
    b = N;
    while (a < b) { int m = (a + b) >> 1; if (bidx[m] < g + 1) a = m + 1; else b = m; }
    const int hi = a;

    const int tid = threadIdx.x;
    const int c4 = tid & 15, nl = tid >> 4;
    float4 s = make_float4(0.f, 0.f, 0.f, 0.f);
    for (int n = lo + nl; n < hi; n += 16) {
        const float4 v = *(const float4*)&Y[(size_t)n * HID + c4 * 4];
        s.x += v.x; s.y += v.y; s.z += v.z; s.w += v.w;
    }
    __shared__ float red[16 * 68];
    *(float4*)&red[nl * 68 + c4 * 4] = s;
    __syncthreads();
    if (tid < 64) {
        float t = 0.f;
        #pragma unroll
        for (int r = 0; r < 16; r++) t += red[r * 68 + tid];
        t *= Ww[tid];
        #pragma unroll
        for (int off = 32; off; off >>= 1) t += __shfl_down(t, off);
        if (tid == 0) out[g] = t + Wb[0];
    }
}

extern "C" void kernel_launch(void* const* d_in, const int* in_sizes, int n_in,
                              void* d_out, int out_size, void* d_ws, size_t ws_size,
                              hipStream_t stream) {
    const float* H    = (const float*)d_in[0];
    const float* Xe   = (const float*)d_in[1];
    const int*   ids  = (const int*)d_in[2];
    const int*   bidx = (const int*)d_in[3];
    const float* Mw0  = (const float*)d_in[4];
    const float* Mb0  = (const float*)d_in[5];
    const float* Uw0  = (const float*)d_in[6];
    const float* Ub0  = (const float*)d_in[7];
    const float* MwH  = (const float*)d_in[8];   // [3, 80, 64]
    const float* MbH  = (const float*)d_in[9];
    const float* UwH  = (const float*)d_in[10];  // [3, 128, 64]
    const float* UbH  = (const float*)d_in[11];
    const float* Ww   = (const float*)d_in[12];
    const float* Wb   = (const float*)d_in[13];
    float* out = (float*)d_out;

    const int N = in_sizes[0] / 32;
    const int E = in_sizes[1] / 16;
    const int* src = ids;
    const int* dst = ids + E;

    // ---- workspace (same total footprint as baseline):
    // bufA: PMa,Tha (N*256B) | bufB: PMb,Thb (N*256B) | Xes E*32B | pks E*4B
    // | rowptr | deg | bsums.  Final-layer f32 y overwrites bufA.
    __half* PMa  = (__half*)d_ws;                       // N*64 h
    __half* Tha  = PMa + (size_t)N * HID;               // N*64 h
    __half* PMb  = Tha + (size_t)N * HID;               // N*64 h
    __half* Thb  = PMb + (size_t)N * HID;               // N*64 h
    float*  yfin = (float*)d_ws;                        // N*64 f32 (= PMa+Tha)
    __half* Xes  = Thb + (size_t)N * HID;               // E*16 h
    unsigned* pks = (unsigned*)(Xes + (size_t)E * 16);  // E u32
    int* rowptr  = (int*)(pks + E);                     // N+1
    int* deg     = rowptr + (N + 1);                    // N
    int* bsums   = deg + N;                             // <=4096

    const int NB = (N + 2047) / 2048;
    const int eblocks = (E + 255) / 256;
    const int ntile   = (N + 31) / 32;

    // ---- CSR build + fp16 edge reorder ----
    hipMemsetAsync(deg, 0, (size_t)N * sizeof(int), stream);
    deg_count<<<eblocks, 256, 0, stream>>>(dst, deg, E);
    scan1<<<NB, 256, 0, stream>>>(deg, rowptr, bsums, N);
    scan2<<<1, 64, 0, stream>>>(bsums, NB);
    scan3<<<(N + 255) / 256, 256, 0, stream>>>(rowptr, bsums, N, E);
    hipMemsetAsync(deg, 0, (size_t)N * sizeof(int), stream);
    permute_k<<<eblocks, 256, 0, stream>>>(src, dst, rowptr, deg,
                                           Xe, Xes, pks, E);

    const float* MwH0 = MwH;                 const float* UwH0 = UwH;
    const float* MwH1 = MwH + 80 * HID;      const float* UwH1 = UwH + 128 * HID;
    const float* MwH2 = MwH + 2 * 80 * HID;  const float* UwH2 = UwH + 2 * 128 * HID;

    // ---- layer 0 (K1=32): pm from H, edge+fused-pm(next=H1 tops) ----
    pm_dual<32><<<ntile, 256, 0, stream>>>(H, Mw0, Mb0, Uw0, Ub0, PMa, Tha, N);
    edge_fused<true><<<ntile, 256, 0, stream>>>(
        PMa, Tha, Xes, pks, rowptr,
        Mw0 + 32 * HID, Uw0 + 32 * HID,
        MwH0, MbH, UwH0, UbH,
        PMb, Thb, nullptr, N);

    // ---- hidden layer 1: read B, fuse pm(next=H2 tops) -> A ----
    edge_fused<true><<<ntile, 256, 0, stream>>>(
        PMb, Thb, Xes, pks, rowptr,
        MwH0 + 64 * HID, UwH0 + 64 * HID,
        MwH1, MbH + HID, UwH1, UbH + HID,
        PMa, Tha, nullptr, N);

    // ---- hidden layer 2: read A, fuse pm(next=H3 tops) -> B ----
    edge_fused<true><<<ntile, 256, 0, stream>>>(
        PMa, Tha, Xes, pks, rowptr,
        MwH1 + 64 * HID, UwH1 + 64 * HID,
        MwH2, MbH + 2 * HID, UwH2, UbH + 2 * HID,
        PMb, Thb, nullptr, N);

    // ---- hidden layer 3 (last): read B, write f32 y into bufA ----
    edge_fused<false><<<ntile, 256, 0, stream>>>(
        PMb, Thb, Xes, pks, rowptr,
        MwH2 + 64 * HID, UwH2 + 64 * HID,
        nullptr, nullptr, nullptr, nullptr,
        nullptr, nullptr, yfin, N);

    // ---- pooling + head ----
    pool_head<<<256, 256, 0, stream>>>(yfin, bidx, Ww, Wb, out, N);
}

// Round 9
// 963.543 us; speedup vs baseline: 1.3071x; 1.3071x over previous
//
#include <hip/hip_runtime.h>
#include <hip/hip_fp16.h>

#define HID 64

struct alignas(8)  H4 { __half2 a, b; };
struct alignas(16) H8 { __half2 h[4]; };

typedef _Float16 h2n __attribute__((ext_vector_type(2)));

__device__ inline float dot2f(__half2 a, __half2 b, float c) {
#if __has_builtin(__builtin_amdgcn_fdot2)
    h2n an, bn;
    __builtin_memcpy(&an, &a, 4);
    __builtin_memcpy(&bn, &b, 4);
    return __builtin_amdgcn_fdot2(an, bn, c, false);
#else
    float2 af = __half22float2(a), bf = __half22float2(b);
    return c + af.x * bf.x + af.y * bf.y;
#endif
}

// ===========================================================================
// CSR build: histogram + scan + permutation (+ fp16 edge-feature reorder)
// ===========================================================================
__global__ __launch_bounds__(256) void deg_count(const int* __restrict__ dst,
                                                 int* __restrict__ deg, int E) {
    int e = blockIdx.x * 256 + threadIdx.x;
    if (e < E) atomicAdd(&deg[dst[e]], 1);
}

__global__ __launch_bounds__(256) void scan1(const int* __restrict__ deg,
                                             int* __restrict__ rowptr,
                                             int* __restrict__ bsums, int N) {
    __shared__ int s[256];
    const int t = threadIdx.x;
    const int base = blockIdx.x * 2048 + t * 8;
    int v[8], tot = 0;
    #pragma unroll
    for (int i = 0; i < 8; i++) {
        int x = (base + i < N) ? deg[base + i] : 0;
        v[i] = tot; tot += x;
    }
    s[t] = tot; __syncthreads();
    for (int off = 1; off < 256; off <<= 1) {
        int a = (t >= off) ? s[t - off] : 0;
        __syncthreads(); s[t] += a; __syncthreads();
    }
    const int texcl = s[t] - tot;
    #pragma unroll
    for (int i = 0; i < 8; i++)
        if (base + i < N) rowptr[base + i] = texcl + v[i];
    if (t == 255) bsums[blockIdx.x] = s[255];
}

__global__ void scan2(int* bsums, int NB) {
    if (blockIdx.x == 0 && threadIdx.x == 0) {
        int run = 0;
        for (int i = 0; i < NB; i++) { int x = bsums[i]; bsums[i] = run; run += x; }
    }
}

__global__ __launch_bounds__(256) void scan3(int* __restrict__ rowptr,
                                             const int* __restrict__ bsums,
                                             int N, int E) {
    int idx = blockIdx.x * 256 + threadIdx.x;
    if (idx < N) rowptr[idx] += bsums[idx >> 11];
    if (idx == 0) rowptr[N] = E;
}

__global__ __launch_bounds__(256) void permute_k(
    const int* __restrict__ src, const int* __restrict__ dst,
    const int* __restrict__ rowptr, int* __restrict__ cursor,
    const float* __restrict__ Xe, __half* __restrict__ Xes,
    unsigned* __restrict__ pks, int E)
{
    int e = blockIdx.x * 256 + threadIdx.x;
    if (e >= E) return;
    int d = dst[e];
    int pos = rowptr[d] + atomicAdd(&cursor[d], 1);
    pks[pos] = ((unsigned)src[e] << 5) | (unsigned)(d & 31);
    const float4* xi = (const float4*)&Xe[(size_t)e * 16];
    float4 x0 = xi[0], x1 = xi[1], x2 = xi[2], x3 = xi[3];
    H8 h0, h1;
    h0.h[0] = __float22half2_rn(make_float2(x0.x, x0.y));
    h0.h[1] = __float22half2_rn(make_float2(x0.z, x0.w));
    h0.h[2] = __float22half2_rn(make_float2(x1.x, x1.y));
    h0.h[3] = __float22half2_rn(make_float2(x1.z, x1.w));
    h1.h[0] = __float22half2_rn(make_float2(x2.x, x2.y));
    h1.h[1] = __float22half2_rn(make_float2(x2.z, x2.w));
    h1.h[2] = __float22half2_rn(make_float2(x3.x, x3.y));
    h1.h[3] = __float22half2_rn(make_float2(x3.z, x3.w));
    H8* xo = (H8*)&Xes[(size_t)pos * 16];
    xo[0] = h0; xo[1] = h1;
}

// ===========================================================================
// pm_dual: PMh[n] = fp16(h@Wm_top + bm), Th[n] = fp16(h@Wu_top + bu)
// (only used for layer 0; hidden-layer PM/Th are fused into edge_fused)
// ===========================================================================
template<int K1>
__global__ __launch_bounds__(256) void pm_dual(
    const float* __restrict__ Hn,
    const float* __restrict__ Wm, const float* __restrict__ bm,
    const float* __restrict__ Wu, const float* __restrict__ bu,
    __half* __restrict__ PMh, __half* __restrict__ Th, int N)
{
    constexpr int KP = K1 + 4;
    constexpr int P4 = K1 / 4;
    __shared__ float Ws[K1 * 128];
    __shared__ float Xs[32 * KP];

    const int tid = threadIdx.x;
    for (int i = tid; i < K1 * 32; i += 256) {
        const int row = i >> 5, c4 = i & 31;
        float4 v = (c4 < 16) ? *(const float4*)&Wm[row * 64 + c4 * 4]
                             : *(const float4*)&Wu[row * 64 + (c4 - 16) * 4];
        *(float4*)&Ws[row * 128 + c4 * 4] = v;
    }
    const int nbase = blockIdx.x * 32;
    for (int i = tid; i < 32 * P4; i += 256) {
        const int nl = i / P4, part = i % P4;
        const int n = nbase + nl;
        if (n < N)
            *(float4*)&Xs[nl * KP + part * 4] =
                *(const float4*)&Hn[(size_t)n * K1 + part * 4];
    }
    __syncthreads();

    const int c0 = (tid & 31) * 4;
    const int n0 = (tid >> 5) * 4;
    const float4 bv = (c0 < 64) ? *(const float4*)&bm[c0]
                                : *(const float4*)&bu[c0 - 64];

    float4 acc[4];
    #pragma unroll
    for (int i = 0; i < 4; i++) acc[i] = bv;

    #pragma unroll 4
    for (int k = 0; k < K1; k += 4) {
        const float4 w0 = *(const float4*)&Ws[(k + 0) * 128 + c0];
        const float4 w1 = *(const float4*)&Ws[(k + 1) * 128 + c0];
        const float4 w2 = *(const float4*)&Ws[(k + 2) * 128 + c0];
        const float4 w3 = *(const float4*)&Ws[(k + 3) * 128 + c0];
        #pragma unroll
        for (int ni = 0; ni < 4; ni++) {
            const float4 xv = *(const float4*)&Xs[(n0 + ni) * KP + k];
            acc[ni].x += xv.x * w0.x + xv.y * w1.x + xv.z * w2.x + xv.w * w3.x;
            acc[ni].y += xv.x * w0.y + xv.y * w1.y + xv.z * w2.y + xv.w * w3.y;
            acc[ni].z += xv.x * w0.z + xv.y * w1.z + xv.z * w2.z + xv.w * w3.z;
            acc[ni].w += xv.x * w0.w + xv.y * w1.w + xv.z * w2.w + xv.w * w3.w;
        }
    }

    #pragma unroll
    for (int ni = 0; ni < 4; ni++) {
        const int n = nbase + n0 + ni;
        if (n < N) {
            H4 o;
            o.a = __float22half2_rn(make_float2(acc[ni].x, acc[ni].y));
            o.b = __float22half2_rn(make_float2(acc[ni].z, acc[ni].w));
            if (c0 < 64) *(H4*)&PMh[(size_t)n * 64 + c0]      = o;
            else         *(H4*)&Th [(size_t)n * 64 + c0 - 64] = o;
        }
    }
}

// ===========================================================================
// edge_fused v7: R7 semantics, honest 64-VGPR diet via 2-cols-per-lane.
//  Lane layout: hw = lane>>5 owns edges [hw*8, hw*8+8) of the 16-edge chunk;
//  c2 = (lane&31)*2 = 2 output cols. wh halves to 16 VGPR; ph[8] half2 = 8;
//  pk[8] = 8 (uniform-per-halfwave addresses -> L1 broadcast); xt = 2.
//  Per-wave LDS Xes staging kept from v6 (coalesced 8B/lane, SLOT=48).
//  Single-deep pipeline: pk loads issued pre-compute (latency hidden under
//  compute), PM gathers post-compute; TLP at the 64-VGPR tier (8 waves/EU
//  forced) covers gather latency -- that is the experiment.
//  R8 lesson: launch_bounds(256,8) with ~75 live regs => 490 MB spill
//  traffic. This version's true live state is ~56.
// ===========================================================================
template<bool FUSE>
__global__ __launch_bounds__(256, 8) void edge_fused(
    const __half*   __restrict__ PMh,   // [N, 64]
    const __half*   __restrict__ Th,    // [N, 64]
    const __half*   __restrict__ Xes,   // [E, 16] dst-sorted
    const unsigned* __restrict__ pks,   // [E] (src<<5)|ld
    const int*      __restrict__ rowptr,
    const float*    __restrict__ Mwb,   // [16, 64] message bottom
    const float*    __restrict__ Uwb,   // [64, 64] update bottom
    const float*    __restrict__ MwN,   // [64, 64] next-layer M top (FUSE)
    const float*    __restrict__ MbN,
    const float*    __restrict__ UwN,   // [64, 64] next-layer U top (FUSE)
    const float*    __restrict__ UbN,
    __half*         __restrict__ PMo,   // [N, 64] out (FUSE)
    __half*         __restrict__ Tho,   // [N, 64] out (FUSE)
    float*          __restrict__ Yout,  // [N, 64] out (!FUSE, final layer)
    int N)
{
    constexpr int AGP  = HID + 4;
    constexpr int SLOT = 48;                 // bytes per staged edge (16-aligned)
    __shared__ float aggs[32 * AGP];         // 8704 B
    __shared__ char  xsh[4][2][16 * SLOT];   // 6144 B per-wave dbuf

    const int tid  = threadIdx.x;
    const int wv   = tid >> 6;
    const int lane = tid & 63;
    const int hw   = lane >> 5;              // half-wave edge-set select
    const int c2   = (lane & 31) * 2;        // 2 output cols per lane
    const int laneE = lane >> 2;             // edge this lane stages (0..15)
    const int laneP = (lane & 3) * 8;        // byte part of the 32B record

    // wh[p][j] = (Mwb[2p][c2+j], Mwb[2p+1][c2+j]), j = 0,1  -> 16 VGPR
    __half2 wh[8][2];
    #pragma unroll
    for (int p = 0; p < 8; p++)
        #pragma unroll
        for (int j = 0; j < 2; j++)
            wh[p][j] = __float22half2_rn(make_float2(Mwb[(2 * p) * 64 + c2 + j],
                                                     Mwb[(2 * p + 1) * 64 + c2 + j]));

    for (int i = tid; i < 32 * AGP; i += 256) aggs[i] = 0.f;

    const int nbase  = blockIdx.x * 32;
    const int nend   = (nbase + 32 < N) ? nbase + 32 : N;
    const int estart = rowptr[nbase];
    const int eend   = rowptr[nend];
    __syncthreads();

    const int pc0 = estart + wv * 16;

    unsigned pk[8];              // pks of the NEXT chunk's 8 owned edges
    __half2  ph[8];              // PM gathers of the CURRENT chunk
    unsigned ldp0, ldp1;         // packed 5-bit local-dst of CURRENT chunk
    uint2    xt;                 // staged 8B of Xes (load ... ds_write)

#define PKLOAD(PC) do {                                                       \
    _Pragma("unroll")                                                         \
    for (int s = 0; s < 8; s++) {                                             \
        const int pe_ = (PC) + hw * 8 + s;                                    \
        pk[s] = pks[pe_ < eend ? pe_ : eend - 1];                             \
    }                                                                         \
} while (0)

    // GATHER: consume pk -> issue PM gathers + pack ldp (for the chunk the
    // pk values belong to).
#define GATHER() do {                                                         \
    unsigned l0_ = 0, l1_ = 0;                                                \
    _Pragma("unroll")                                                         \
    for (int s = 0; s < 8; s++) {                                             \
        const unsigned pk_ = pk[s];                                           \
        ph[s] = *(const __half2*)((const char*)PMh +                          \
                                  ((size_t)(pk_ >> 5) << 7) + c2 * 2);        \
        if (s < 4) l0_ |= (pk_ & 31u) << (8 * s);                             \
        else       l1_ |= (pk_ & 31u) << (8 * (s - 4));                       \
    }                                                                         \
    ldp0 = l0_; ldp1 = l1_;                                                   \
} while (0)

#define LOADX(CB) do {                                                        \
    const int pe_  = (CB) + laneE;                                            \
    const int pcl_ = pe_ < eend ? pe_ : eend - 1;                             \
    xt = *(const uint2*)((const char*)Xes + (size_t)pcl_ * 32 + laneP);       \
} while (0)

#define WRITEX(BUF)                                                           \
    *(uint2*)&xsh[wv][BUF][laneE * SLOT + laneP] = xt

#define COMPUTE(BUF, PCC) do {                                                \
    int ld_prev = -1;                                                         \
    float r0 = 0.f, r1 = 0.f;                                                 \
    _Pragma("unroll")                                                         \
    for (int s = 0; s < 8; s++) {                                             \
        const int e_ = hw * 8 + s;                                            \
        const H8 x0 = *(const H8*)&xsh[wv][BUF][e_ * SLOT];                   \
        const H8 x1 = *(const H8*)&xsh[wv][BUF][e_ * SLOT + 16];              \
        const float2 pf = __half22float2(ph[s]);                              \
        float a0 = pf.x, a1 = pf.y;                                           \
        _Pragma("unroll")                                                     \
        for (int p = 0; p < 4; p++) {                                         \
            const __half2 xv = x0.h[p];                                       \
            a0 = dot2f(xv, wh[p][0], a0); a1 = dot2f(xv, wh[p][1], a1);       \
        }                                                                     \
        _Pragma("unroll")                                                     \
        for (int p = 0; p < 4; p++) {                                         \
            const __half2 xv = x1.h[p];                                       \
            a0 = dot2f(xv, wh[p+4][0], a0); a1 = dot2f(xv, wh[p+4][1], a1);   \
        }                                                                     \
        a0 = fmaxf(a0, 0.f); a1 = fmaxf(a1, 0.f);                             \
        const int ld = ((PCC) + e_ < eend)                                    \
            ? (int)(((s < 4 ? ldp0 >> (8 * s) : ldp1 >> (8 * (s - 4)))) & 31u)\
            : -1;                                                             \
        if (ld == ld_prev) {                                                  \
            r0 += a0; r1 += a1;                                               \
        } else {                                                              \
            if (ld_prev >= 0) {                                               \
                float* a_ = &aggs[ld_prev * AGP + c2];                        \
                atomicAdd(a_ + 0, r0); atomicAdd(a_ + 1, r1);                 \
            }                                                                 \
            r0 = a0; r1 = a1; ld_prev = ld;                                   \
        }                                                                     \
    }                                                                         \
    if (ld_prev >= 0) {                                                       \
        float* a_ = &aggs[ld_prev * AGP + c2];                                \
        atomicAdd(a_ + 0, r0); atomicAdd(a_ + 1, r1);                         \
    }                                                                         \
} while (0)

    if (pc0 < eend) {
        // prologue: pk+gathers for chunk0, stage chunk0 Xes into buf0
        PKLOAD(pc0);
        GATHER();                // ph,ldp <- chunk0
        LOADX(pc0);
        WRITEX(0);

        // iter (chunk i, buf=i&1): pk/xt <- chunk i+1 (latency under compute),
        // COMPUTE chunk i, then gathers for i+1, stage xt into other buf.
        int pc = pc0;
        while (true) {
            { PKLOAD(pc + 64); LOADX(pc + 64);
              COMPUTE(0, pc);
              GATHER(); WRITEX(1); }
            pc += 64; if (pc >= eend) break;
            { PKLOAD(pc + 64); LOADX(pc + 64);
              COMPUTE(1, pc);
              GATHER(); WRITEX(0); }
            pc += 64; if (pc >= eend) break;
        }
    }

#undef PKLOAD
#undef GATHER
#undef LOADX
#undef WRITEX
#undef COMPUTE

    __syncthreads();

    // ---- fused node update: y = relu(T + aggs @ Uw_bot), Uwb via L1 ----
    const int c0t = (tid & 15) * 4;
    const int r0  = tid >> 4;
    const int r1  = r0 + 16;
    const int n0g = nbase + r0, n1g = nbase + r1;
    float4 acc0 = make_float4(0.f, 0.f, 0.f, 0.f);
    float4 acc1 = make_float4(0.f, 0.f, 0.f, 0.f);
    if (n0g < N) {
        H4 th = *(const H4*)&Th[(size_t)n0g * 64 + c0t];
        float2 lo = __half22float2(th.a), hi = __half22float2(th.b);
        acc0 = make_float4(lo.x, lo.y, hi.x, hi.y);
    }
    if (n1g < N) {
        H4 th = *(const H4*)&Th[(size_t)n1g * 64 + c0t];
        float2 lo = __half22float2(th.a), hi = __half22float2(th.b);
        acc1 = make_float4(lo.x, lo.y, hi.x, hi.y);
    }
    #pragma unroll 4
    for (int k = 0; k < 64; k += 4) {
        const float4 w0 = *(const float4*)&Uwb[(k + 0) * 64 + c0t];
        const float4 w1 = *(const float4*)&Uwb[(k + 1) * 64 + c0t];
        const float4 w2 = *(const float4*)&Uwb[(k + 2) * 64 + c0t];
        const float4 w3 = *(const float4*)&Uwb[(k + 3) * 64 + c0t];
        const float4 x0 = *(const float4*)&aggs[r0 * AGP + k];
        const float4 x1 = *(const float4*)&aggs[r1 * AGP + k];
        acc0.x += x0.x * w0.x + x0.y * w1.x + x0.z * w2.x + x0.w * w3.x;
        acc0.y += x0.x * w0.y + x0.y * w1.y + x0.z * w2.y + x0.w * w3.y;
        acc0.z += x0.x * w0.z + x0.y * w1.z + x0.z * w2.z + x0.w * w3.z;
        acc0.w += x0.x * w0.w + x0.y * w1.w + x0.z * w2.w + x0.w * w3.w;
        acc1.x += x1.x * w0.x + x1.y * w1.x + x1.z * w2.x + x1.w * w3.x;
        acc1.y += x1.x * w0.y + x1.y * w1.y + x1.z * w2.y + x1.w * w3.y;
        acc1.z += x1.x * w0.z + x1.y * w1.z + x1.z * w2.z + x1.w * w3.z;
        acc1.w += x1.x * w0.w + x1.y * w1.w + x1.z * w2.w + x1.w * w3.w;
    }
    float4 y0, y1;
    y0.x = fmaxf(acc0.x, 0.f); y0.y = fmaxf(acc0.y, 0.f);
    y0.z = fmaxf(acc0.z, 0.f); y0.w = fmaxf(acc0.w, 0.f);
    y1.x = fmaxf(acc1.x, 0.f); y1.y = fmaxf(acc1.y, 0.f);
    y1.z = fmaxf(acc1.z, 0.f); y1.w = fmaxf(acc1.w, 0.f);

    if (!FUSE) {
        if (n0g < N) *(float4*)&Yout[(size_t)n0g * HID + c0t] = y0;
        if (n1g < N) *(float4*)&Yout[(size_t)n1g * HID + c0t] = y1;
    } else {
        // ---- in-block pm for NEXT layer: PM/Th = fp16(y@W_top + b) ----
        __syncthreads();                       // all aggs reads done
        *(float4*)&aggs[r0 * AGP + c0t] = y0;  // stage y in aggs
        *(float4*)&aggs[r1 * AGP + c0t] = y1;
        __syncthreads();

        const int c2e = (tid & 31) * 4;        // 0..124 (128 out cols)
        const int nn0 = (tid >> 5) * 4;        // 4 nodes/thread
        const bool isM = (c2e < 64);
        const float* Wn = isM ? MwN : UwN;
        const float* bn = isM ? MbN : UbN;
        const int cc = isM ? c2e : c2e - 64;
        const float4 bv = *(const float4*)&bn[cc];

        #pragma unroll 1
        for (int h = 0; h < 2; h++) {          // two 2-node passes (reg cap)
            const int na = nn0 + 2 * h, nb = na + 1;
            float4 p0 = bv, p1 = bv;
            #pragma unroll 4
            for (int k = 0; k < 64; k += 4) {
                const float4 w0 = *(const float4*)&Wn[(k + 0) * 64 + cc];
                const float4 w1 = *(const float4*)&Wn[(k + 1) * 64 + cc];
                const float4 w2 = *(const float4*)&Wn[(k + 2) * 64 + cc];
                const float4 w3 = *(const float4*)&Wn[(k + 3) * 64 + cc];
                const float4 x0 = *(const float4*)&aggs[na * AGP + k];
                const float4 x1 = *(const float4*)&aggs[nb * AGP + k];
                p0.x += x0.x * w0.x + x0.y * w1.x + x0.z * w2.x + x0.w * w3.x;
                p0.y += x0.x * w0.y + x0.y * w1.y + x0.z * w2.y + x0.w * w3.y;
                p0.z += x0.x * w0.z + x0.y * w1.z + x0.z * w2.z + x0.w * w3.z;
                p0.w += x0.x * w0.w + x0.y * w1.w + x0.z * w2.w + x0.w * w3.w;
                p1.x += x1.x * w0.x + x1.y * w1.x + x1.z * w2.x + x1.w * w3.x;
                p1.y += x1.x * w0.y + x1.y * w1.y + x1.z * w2.y + x1.w * w3.y;
                p1.z += x1.x * w0.z + x1.y * w1.z + x1.z * w2.z + x1.w * w3.z;
                p1.w += x1.x * w0.w + x1.y * w1.w + x1.z * w2.w + x1.w * w3.w;
            }
            if (nbase + na < N) {
                H4 o;
                o.a = __float22half2_rn(make_float2(p0.x, p0.y));
                o.b = __float22half2_rn(make_float2(p0.z, p0.w));
                if (isM) *(H4*)&PMo[(size_t)(nbase + na) * 64 + cc] = o;
                else     *(H4*)&Tho[(size_t)(nbase + na) * 64 + cc] = o;
            }
            if (nbase + nb < N) {
                H4 o;
                o.a = __float22half2_rn(make_float2(p1.x, p1.y));
                o.b = __float22half2_rn(make_float2(p1.z, p1.w));
                if (isM) *(H4*)&PMo[(size_t)(nbase + nb) * 64 + cc] = o;
                else     *(H4*)&Tho[(size_t)(nbase + nb) * 64 + cc] = o;
            }
        }
    }
}

// ===========================================================================
// pool_head: out[g] = (sum_{n in graph g} y[n]) . Ww + Wb  (sorted batch_idx)
// ===========================================================================
__global__ __launch_bounds__(256) void pool_head(
    const float* __restrict__ Y, const int* __restrict__ bidx,
    const float* __restrict__ Ww, const float* __restrict__ Wb,
    float* __restrict__ out, int N)
{
    const int g = blockIdx.x;
    int a = 0, b = N;
    while (a < b) { int m = (a + b) >> 1; if (bidx[m] < g) a = m + 1; else b = m; }
    const int lo = a;
    b = N;
    while (a < b) { int m = (a + b) >> 1; if (bidx[m] < g + 1) a = m + 1; else b = m; }
    const int hi = a;

    const int tid = threadIdx.x;
    const int c4 = tid & 15, nl = tid >> 4;
    float4 s = make_float4(0.f, 0.f, 0.f, 0.f);
    for (int n = lo + nl; n < hi; n += 16) {
        const float4 v = *(const float4*)&Y[(size_t)n * HID + c4 * 4];
        s.x += v.x; s.y += v.y; s.z += v.z; s.w += v.w;
    }
    __shared__ float red[16 * 68];
    *(float4*)&red[nl * 68 + c4 * 4] = s;
    __syncthreads();
    if (tid < 64) {
        float t = 0.f;
        #pragma unroll
        for (int r = 0; r < 16; r++) t += red[r * 68 + tid];
        t *= Ww[tid];
        #pragma unroll
        for (int off = 32; off; off >>= 1) t += __shfl_down(t, off);
        if (tid == 0) out[g] = t + Wb[0];
    }
}

extern "C" void kernel_launch(void* const* d_in, const int* in_sizes, int n_in,
                              void* d_out, int out_size, void* d_ws, size_t ws_size,
                              hipStream_t stream) {
    const float* H    = (const float*)d_in[0];
    const float* Xe   = (const float*)d_in[1];
    const int*   ids  = (const int*)d_in[2];
    const int*   bidx = (const int*)d_in[3];
    const float* Mw0  = (const float*)d_in[4];
    const float* Mb0  = (const float*)d_in[5];
    const float* Uw0  = (const float*)d_in[6];
    const float* Ub0  = (const float*)d_in[7];
    const float* MwH  = (const float*)d_in[8];   // [3, 80, 64]
    const float* MbH  = (const float*)d_in[9];
    const float* UwH  = (const float*)d_in[10];  // [3, 128, 64]
    const float* UbH  = (const float*)d_in[11];
    const float* Ww   = (const float*)d_in[12];
    const float* Wb   = (const float*)d_in[13];
    float* out = (float*)d_out;

    const int N = in_sizes[0] / 32;
    const int E = in_sizes[1] / 16;
    const int* src = ids;
    const int* dst = ids + E;

    // ---- workspace (same total footprint as baseline):
    // bufA: PMa,Tha (N*256B) | bufB: PMb,Thb (N*256B) | Xes E*32B | pks E*4B
    // | rowptr | deg | bsums.  Final-layer f32 y overwrites bufA.
    __half* PMa  = (__half*)d_ws;                       // N*64 h
    __half* Tha  = PMa + (size_t)N * HID;               // N*64 h
    __half* PMb  = Tha + (size_t)N * HID;               // N*64 h
    __half* Thb  = PMb + (size_t)N * HID;               // N*64 h
    float*  yfin = (float*)d_ws;                        // N*64 f32 (= PMa+Tha)
    __half* Xes  = Thb + (size_t)N * HID;               // E*16 h
    unsigned* pks = (unsigned*)(Xes + (size_t)E * 16);  // E u32
    int* rowptr  = (int*)(pks + E);                     // N+1
    int* deg     = rowptr + (N + 1);                    // N
    int* bsums   = deg + N;                             // <=4096

    const int NB = (N + 2047) / 2048;
    const int eblocks = (E + 255) / 256;
    const int ntile   = (N + 31) / 32;

    // ---- CSR build + fp16 edge reorder ----
    hipMemsetAsync(deg, 0, (size_t)N * sizeof(int), stream);
    deg_count<<<eblocks, 256, 0, stream>>>(dst, deg, E);
    scan1<<<NB, 256, 0, stream>>>(deg, rowptr, bsums, N);
    scan2<<<1, 64, 0, stream>>>(bsums, NB);
    scan3<<<(N + 255) / 256, 256, 0, stream>>>(rowptr, bsums, N, E);
    hipMemsetAsync(deg, 0, (size_t)N * sizeof(int), stream);
    permute_k<<<eblocks, 256, 0, stream>>>(src, dst, rowptr, deg,
                                           Xe, Xes, pks, E);

    const float* MwH0 = MwH;                 const float* UwH0 = UwH;
    const float* MwH1 = MwH + 80 * HID;      const float* UwH1 = UwH + 128 * HID;
    const float* MwH2 = MwH + 2 * 80 * HID;  const float* UwH2 = UwH + 2 * 128 * HID;

    // ---- layer 0 (K1=32): pm from H, edge+fused-pm(next=H1 tops) ----
    pm_dual<32><<<ntile, 256, 0, stream>>>(H, Mw0, Mb0, Uw0, Ub0, PMa, Tha, N);
    edge_fused<true><<<ntile, 256, 0, stream>>>(
        PMa, Tha, Xes, pks, rowptr,
        Mw0 + 32 * HID, Uw0 + 32 * HID,
        MwH0, MbH, UwH0, UbH,
        PMb, Thb, nullptr, N);

    // ---- hidden layer 1: read B, fuse pm(next=H2 tops) -> A ----
    edge_fused<true><<<ntile, 256, 0, stream>>>(
        PMb, Thb, Xes, pks, rowptr,
        MwH0 + 64 * HID, UwH0 + 64 * HID,
        MwH1, MbH + HID, UwH1, UbH + HID,
        PMa, Tha, nullptr, N);

    // ---- hidden layer 2: read A, fuse pm(next=H3 tops) -> B ----
    edge_fused<true><<<ntile, 256, 0, stream>>>(
        PMa, Tha, Xes, pks, rowptr,
        MwH1 + 64 * HID, UwH1 + 64 * HID,
        MwH2, MbH + 2 * HID, UwH2, UbH + 2 * HID,
        PMb, Thb, nullptr, N);

    // ---- hidden layer 3 (last): read B, write f32 y into bufA ----
    edge_fused<false><<<ntile, 256, 0, stream>>>(
        PMb, Thb, Xes, pks, rowptr,
        MwH2 + 64 * HID, UwH2 + 64 * HID,
        nullptr, nullptr, nullptr, nullptr,
        nullptr, nullptr, yfin, N);

    // ---- pooling + head ----
    pool_head<<<256, 256, 0, stream>>>(yfin, bidx, Ww, Wb, out, N);
}

// Round 10
// 821.095 us; speedup vs baseline: 1.5339x; 1.1735x over previous
//
#include <hip/hip_runtime.h>
#include <hip/hip_fp16.h>

#define HID 64

struct alignas(8)  H4 { __half2 a, b; };
struct alignas(16) H8 { __half2 h[4]; };

typedef _Float16 h2n __attribute__((ext_vector_type(2)));

__device__ inline float dot2f(__half2 a, __half2 b, float c) {
#if __has_builtin(__builtin_amdgcn_fdot2)
    h2n an, bn;
    __builtin_memcpy(&an, &a, 4);
    __builtin_memcpy(&bn, &b, 4);
    return __builtin_amdgcn_fdot2(an, bn, c, false);
#else
    float2 af = __half22float2(a), bf = __half22float2(b);
    return c + af.x * bf.x + af.y * bf.y;
#endif
}

// ===========================================================================
// CSR build: histogram + scan + permutation (+ fp16 edge-feature reorder)
// ===========================================================================
__global__ __launch_bounds__(256) void deg_count(const int* __restrict__ dst,
                                                 int* __restrict__ deg, int E) {
    int e = blockIdx.x * 256 + threadIdx.x;
    if (e < E) atomicAdd(&deg[dst[e]], 1);
}

__global__ __launch_bounds__(256) void scan1(const int* __restrict__ deg,
                                             int* __restrict__ rowptr,
                                             int* __restrict__ bsums, int N) {
    __shared__ int s[256];
    const int t = threadIdx.x;
    const int base = blockIdx.x * 2048 + t * 8;
    int v[8], tot = 0;
    #pragma unroll
    for (int i = 0; i < 8; i++) {
        int x = (base + i < N) ? deg[base + i] : 0;
        v[i] = tot; tot += x;
    }
    s[t] = tot; __syncthreads();
    for (int off = 1; off < 256; off <<= 1) {
        int a = (t >= off) ? s[t - off] : 0;
        __syncthreads(); s[t] += a; __syncthreads();
    }
    const int texcl = s[t] - tot;
    #pragma unroll
    for (int i = 0; i < 8; i++)
        if (base + i < N) rowptr[base + i] = texcl + v[i];
    if (t == 255) bsums[blockIdx.x] = s[255];
}

__global__ void scan2(int* bsums, int NB) {
    if (blockIdx.x == 0 && threadIdx.x == 0) {
        int run = 0;
        for (int i = 0; i < NB; i++) { int x = bsums[i]; bsums[i] = run; run += x; }
    }
}

__global__ __launch_bounds__(256) void scan3(int* __restrict__ rowptr,
                                             const int* __restrict__ bsums,
                                             int N, int E) {
    int idx = blockIdx.x * 256 + threadIdx.x;
    if (idx < N) rowptr[idx] += bsums[idx >> 11];
    if (idx == 0) rowptr[N] = E;
}

__global__ __launch_bounds__(256) void permute_k(
    const int* __restrict__ src, const int* __restrict__ dst,
    const int* __restrict__ rowptr, int* __restrict__ cursor,
    const float* __restrict__ Xe, __half* __restrict__ Xes,
    unsigned* __restrict__ pks, int E)
{
    int e = blockIdx.x * 256 + threadIdx.x;
    if (e >= E) return;
    int d = dst[e];
    int pos = rowptr[d] + atomicAdd(&cursor[d], 1);
    pks[pos] = ((unsigned)src[e] << 5) | (unsigned)(d & 31);
    const float4* xi = (const float4*)&Xe[(size_t)e * 16];
    float4 x0 = xi[0], x1 = xi[1], x2 = xi[2], x3 = xi[3];
    H8 h0, h1;
    h0.h[0] = __float22half2_rn(make_float2(x0.x, x0.y));
    h0.h[1] = __float22half2_rn(make_float2(x0.z, x0.w));
    h0.h[2] = __float22half2_rn(make_float2(x1.x, x1.y));
    h0.h[3] = __float22half2_rn(make_float2(x1.z, x1.w));
    h1.h[0] = __float22half2_rn(make_float2(x2.x, x2.y));
    h1.h[1] = __float22half2_rn(make_float2(x2.z, x2.w));
    h1.h[2] = __float22half2_rn(make_float2(x3.x, x3.y));
    h1.h[3] = __float22half2_rn(make_float2(x3.z, x3.w));
    H8* xo = (H8*)&Xes[(size_t)pos * 16];
    xo[0] = h0; xo[1] = h1;
}

// ===========================================================================
// pm_dual: PMh[n] = fp16(h@Wm_top + bm), Th[n] = fp16(h@Wu_top + bu)
// (only used for layer 0; hidden-layer PM/Th are fused into edge_fused)
// ===========================================================================
template<int K1>
__global__ __launch_bounds__(256) void pm_dual(
    const float* __restrict__ Hn,
    const float* __restrict__ Wm, const float* __restrict__ bm,
    const float* __restrict__ Wu, const float* __restrict__ bu,
    __half* __restrict__ PMh, __half* __restrict__ Th, int N)
{
    constexpr int KP = K1 + 4;
    constexpr int P4 = K1 / 4;
    __shared__ float Ws[K1 * 128];
    __shared__ float Xs[32 * KP];

    const int tid = threadIdx.x;
    for (int i = tid; i < K1 * 32; i += 256) {
        const int row = i >> 5, c4 = i & 31;
        float4 v = (c4 < 16) ? *(const float4*)&Wm[row * 64 + c4 * 4]
                             : *(const float4*)&Wu[row * 64 + (c4 - 16) * 4];
        *(float4*)&Ws[row * 128 + c4 * 4] = v;
    }
    const int nbase = blockIdx.x * 32;
    for (int i = tid; i < 32 * P4; i += 256) {
        const int nl = i / P4, part = i % P4;
        const int n = nbase + nl;
        if (n < N)
            *(float4*)&Xs[nl * KP + part * 4] =
                *(const float4*)&Hn[(size_t)n * K1 + part * 4];
    }
    __syncthreads();

    const int c0 = (tid & 31) * 4;
    const int n0 = (tid >> 5) * 4;
    const float4 bv = (c0 < 64) ? *(const float4*)&bm[c0]
                                : *(const float4*)&bu[c0 - 64];

    float4 acc[4];
    #pragma unroll
    for (int i = 0; i < 4; i++) acc[i] = bv;

    #pragma unroll 4
    for (int k = 0; k < K1; k += 4) {
        const float4 w0 = *(const float4*)&Ws[(k + 0) * 128 + c0];
        const float4 w1 = *(const float4*)&Ws[(k + 1) * 128 + c0];
        const float4 w2 = *(const float4*)&Ws[(k + 2) * 128 + c0];
        const float4 w3 = *(const float4*)&Ws[(k + 3) * 128 + c0];
        #pragma unroll
        for (int ni = 0; ni < 4; ni++) {
            const float4 xv = *(const float4*)&Xs[(n0 + ni) * KP + k];
            acc[ni].x += xv.x * w0.x + xv.y * w1.x + xv.z * w2.x + xv.w * w3.x;
            acc[ni].y += xv.x * w0.y + xv.y * w1.y + xv.z * w2.y + xv.w * w3.y;
            acc[ni].z += xv.x * w0.z + xv.y * w1.z + xv.z * w2.z + xv.w * w3.z;
            acc[ni].w += xv.x * w0.w + xv.y * w1.w + xv.z * w2.w + xv.w * w3.w;
        }
    }

    #pragma unroll
    for (int ni = 0; ni < 4; ni++) {
        const int n = nbase + n0 + ni;
        if (n < N) {
            H4 o;
            o.a = __float22half2_rn(make_float2(acc[ni].x, acc[ni].y));
            o.b = __float22half2_rn(make_float2(acc[ni].z, acc[ni].w));
            if (c0 < 64) *(H4*)&PMh[(size_t)n * 64 + c0]      = o;
            else         *(H4*)&Th [(size_t)n * 64 + c0 - 64] = o;
        }
    }
}

// ===========================================================================
// edge_fused v8: R9's 2-cols-per-lane structure, UNFORCED launch bounds.
//  R8/R9 lesson: __launch_bounds__(256,8) on gfx950 pins arch-VGPR at 32
//  (unified-file split artifact) -> 26+ regs spilled to scratch -> 260-490MB
//  of spill traffic. Here the allocator runs free: true live state ~56-62;
//  if it lands <=64 we get the 32-wave/CU tier naturally (LDS 14.8KB x 8
//  blocks = 119KB < 160KB), else we're at R7-par with less VALU work.
// ===========================================================================
template<bool FUSE>
__global__ __launch_bounds__(256) void edge_fused(
    const __half*   __restrict__ PMh,   // [N, 64]
    const __half*   __restrict__ Th,    // [N, 64]
    const __half*   __restrict__ Xes,   // [E, 16] dst-sorted
    const unsigned* __restrict__ pks,   // [E] (src<<5)|ld
    const int*      __restrict__ rowptr,
    const float*    __restrict__ Mwb,   // [16, 64] message bottom
    const float*    __restrict__ Uwb,   // [64, 64] update bottom
    const float*    __restrict__ MwN,   // [64, 64] next-layer M top (FUSE)
    const float*    __restrict__ MbN,
    const float*    __restrict__ UwN,   // [64, 64] next-layer U top (FUSE)
    const float*    __restrict__ UbN,
    __half*         __restrict__ PMo,   // [N, 64] out (FUSE)
    __half*         __restrict__ Tho,   // [N, 64] out (FUSE)
    float*          __restrict__ Yout,  // [N, 64] out (!FUSE, final layer)
    int N)
{
    constexpr int AGP  = HID + 4;
    constexpr int SLOT = 48;                 // bytes per staged edge (16-aligned)
    __shared__ float aggs[32 * AGP];         // 8704 B
    __shared__ char  xsh[4][2][16 * SLOT];   // 6144 B per-wave dbuf

    const int tid  = threadIdx.x;
    const int wv   = tid >> 6;
    const int lane = tid & 63;
    const int hw   = lane >> 5;              // half-wave edge-set select
    const int c2   = (lane & 31) * 2;        // 2 output cols per lane
    const int laneE = lane >> 2;             // edge this lane stages (0..15)
    const int laneP = (lane & 3) * 8;        // byte part of the 32B record

    // wh[p][j] = (Mwb[2p][c2+j], Mwb[2p+1][c2+j]), j = 0,1  -> 16 VGPR
    __half2 wh[8][2];
    #pragma unroll
    for (int p = 0; p < 8; p++)
        #pragma unroll
        for (int j = 0; j < 2; j++)
            wh[p][j] = __float22half2_rn(make_float2(Mwb[(2 * p) * 64 + c2 + j],
                                                     Mwb[(2 * p + 1) * 64 + c2 + j]));

    for (int i = tid; i < 32 * AGP; i += 256) aggs[i] = 0.f;

    const int nbase  = blockIdx.x * 32;
    const int nend   = (nbase + 32 < N) ? nbase + 32 : N;
    const int estart = rowptr[nbase];
    const int eend   = rowptr[nend];
    __syncthreads();

    const int pc0 = estart + wv * 16;

    unsigned pk[8];              // pks of the NEXT chunk's 8 owned edges
    __half2  ph[8];              // PM gathers of the CURRENT chunk
    unsigned ldp0, ldp1;         // packed 5-bit local-dst of CURRENT chunk
    uint2    xt;                 // staged 8B of Xes (load ... ds_write)

#define PKLOAD(PC) do {                                                       \
    _Pragma("unroll")                                                         \
    for (int s = 0; s < 8; s++) {                                             \
        const int pe_ = (PC) + hw * 8 + s;                                    \
        pk[s] = pks[pe_ < eend ? pe_ : eend - 1];                             \
    }                                                                         \
} while (0)

    // GATHER: consume pk -> issue PM gathers + pack ldp (for the chunk the
    // pk values belong to).
#define GATHER() do {                                                         \
    unsigned l0_ = 0, l1_ = 0;                                                \
    _Pragma("unroll")                                                         \
    for (int s = 0; s < 8; s++) {                                             \
        const unsigned pk_ = pk[s];                                           \
        ph[s] = *(const __half2*)((const char*)PMh +                          \
                                  ((size_t)(pk_ >> 5) << 7) + c2 * 2);        \
        if (s < 4) l0_ |= (pk_ & 31u) << (8 * s);                             \
        else       l1_ |= (pk_ & 31u) << (8 * (s - 4));                       \
    }                                                                         \
    ldp0 = l0_; ldp1 = l1_;                                                   \
} while (0)

#define LOADX(CB) do {                                                        \
    const int pe_  = (CB) + laneE;                                            \
    const int pcl_ = pe_ < eend ? pe_ : eend - 1;                             \
    xt = *(const uint2*)((const char*)Xes + (size_t)pcl_ * 32 + laneP);       \
} while (0)

#define WRITEX(BUF)                                                           \
    *(uint2*)&xsh[wv][BUF][laneE * SLOT + laneP] = xt

#define COMPUTE(BUF, PCC) do {                                                \
    int ld_prev = -1;                                                         \
    float r0 = 0.f, r1 = 0.f;                                                 \
    _Pragma("unroll")                                                         \
    for (int s = 0; s < 8; s++) {                                             \
        const int e_ = hw * 8 + s;                                            \
        const H8 x0 = *(const H8*)&xsh[wv][BUF][e_ * SLOT];                   \
        const H8 x1 = *(const H8*)&xsh[wv][BUF][e_ * SLOT + 16];              \
        const float2 pf = __half22float2(ph[s]);                              \
        float a0 = pf.x, a1 = pf.y;                                           \
        _Pragma("unroll")                                                     \
        for (int p = 0; p < 4; p++) {                                         \
            const __half2 xv = x0.h[p];                                       \
            a0 = dot2f(xv, wh[p][0], a0); a1 = dot2f(xv, wh[p][1], a1);       \
        }                                                                     \
        _Pragma("unroll")                                                     \
        for (int p = 0; p < 4; p++) {                                         \
            const __half2 xv = x1.h[p];                                       \
            a0 = dot2f(xv, wh[p+4][0], a0); a1 = dot2f(xv, wh[p+4][1], a1);   \
        }                                                                     \
        a0 = fmaxf(a0, 0.f); a1 = fmaxf(a1, 0.f);                             \
        const int ld = ((PCC) + e_ < eend)                                    \
            ? (int)(((s < 4 ? ldp0 >> (8 * s) : ldp1 >> (8 * (s - 4)))) & 31u)\
            : -1;                                                             \
        if (ld == ld_prev) {                                                  \
            r0 += a0; r1 += a1;                                               \
        } else {                                                              \
            if (ld_prev >= 0) {                                               \
                float* a_ = &aggs[ld_prev * AGP + c2];                        \
                atomicAdd(a_ + 0, r0); atomicAdd(a_ + 1, r1);                 \
            }                                                                 \
            r0 = a0; r1 = a1; ld_prev = ld;                                   \
        }                                                                     \
    }                                                                         \
    if (ld_prev >= 0) {                                                       \
        float* a_ = &aggs[ld_prev * AGP + c2];                                \
        atomicAdd(a_ + 0, r0); atomicAdd(a_ + 1, r1);                         \
    }                                                                         \
} while (0)

    if (pc0 < eend) {
        // prologue: pk+gathers for chunk0, stage chunk0 Xes into buf0
        PKLOAD(pc0);
        GATHER();                // ph,ldp <- chunk0
        LOADX(pc0);
        WRITEX(0);

        // iter (chunk i, buf=i&1): pk/xt <- chunk i+1 (latency under compute),
        // COMPUTE chunk i, then gathers for i+1, stage xt into other buf.
        int pc = pc0;
        while (true) {
            { PKLOAD(pc + 64); LOADX(pc + 64);
              COMPUTE(0, pc);
              GATHER(); WRITEX(1); }
            pc += 64; if (pc >= eend) break;
            { PKLOAD(pc + 64); LOADX(pc + 64);
              COMPUTE(1, pc);
              GATHER(); WRITEX(0); }
            pc += 64; if (pc >= eend) break;
        }
    }

#undef PKLOAD
#undef GATHER
#undef LOADX
#undef WRITEX
#undef COMPUTE

    __syncthreads();

    // ---- fused node update: y = relu(T + aggs @ Uw_bot), Uwb via L1 ----
    const int c0t = (tid & 15) * 4;
    const int r0  = tid >> 4;
    const int r1  = r0 + 16;
    const int n0g = nbase + r0, n1g = nbase + r1;
    float4 acc0 = make_float4(0.f, 0.f, 0.f, 0.f);
    float4 acc1 = make_float4(0.f, 0.f, 0.f, 0.f);
    if (n0g < N) {
        H4 th = *(const H4*)&Th[(size_t)n0g * 64 + c0t];
        float2 lo = __half22float2(th.a), hi = __half22float2(th.b);
        acc0 = make_float4(lo.x, lo.y, hi.x, hi.y);
    }
    if (n1g < N) {
        H4 th = *(const H4*)&Th[(size_t)n1g * 64 + c0t];
        float2 lo = __half22float2(th.a), hi = __half22float2(th.b);
        acc1 = make_float4(lo.x, lo.y, hi.x, hi.y);
    }
    #pragma unroll 4
    for (int k = 0; k < 64; k += 4) {
        const float4 w0 = *(const float4*)&Uwb[(k + 0) * 64 + c0t];
        const float4 w1 = *(const float4*)&Uwb[(k + 1) * 64 + c0t];
        const float4 w2 = *(const float4*)&Uwb[(k + 2) * 64 + c0t];
        const float4 w3 = *(const float4*)&Uwb[(k + 3) * 64 + c0t];
        const float4 x0 = *(const float4*)&aggs[r0 * AGP + k];
        const float4 x1 = *(const float4*)&aggs[r1 * AGP + k];
        acc0.x += x0.x * w0.x + x0.y * w1.x + x0.z * w2.x + x0.w * w3.x;
        acc0.y += x0.x * w0.y + x0.y * w1.y + x0.z * w2.y + x0.w * w3.y;
        acc0.z += x0.x * w0.z + x0.y * w1.z + x0.z * w2.z + x0.w * w3.z;
        acc0.w += x0.x * w0.w + x0.y * w1.w + x0.z * w2.w + x0.w * w3.w;
        acc1.x += x1.x * w0.x + x1.y * w1.x + x1.z * w2.x + x1.w * w3.x;
        acc1.y += x1.x * w0.y + x1.y * w1.y + x1.z * w2.y + x1.w * w3.y;
        acc1.z += x1.x * w0.z + x1.y * w1.z + x1.z * w2.z + x1.w * w3.z;
        acc1.w += x1.x * w0.w + x1.y * w1.w + x1.z * w2.w + x1.w * w3.w;
    }
    float4 y0, y1;
    y0.x = fmaxf(acc0.x, 0.f); y0.y = fmaxf(acc0.y, 0.f);
    y0.z = fmaxf(acc0.z, 0.f); y0.w = fmaxf(acc0.w, 0.f);
    y1.x = fmaxf(acc1.x, 0.f); y1.y = fmaxf(acc1.y, 0.f);
    y1.z = fmaxf(acc1.z, 0.f); y1.w = fmaxf(acc1.w, 0.f);

    if (!FUSE) {
        if (n0g < N) *(float4*)&Yout[(size_t)n0g * HID + c0t] = y0;
        if (n1g < N) *(float4*)&Yout[(size_t)n1g * HID + c0t] = y1;
    } else {
        // ---- in-block pm for NEXT layer: PM/Th = fp16(y@W_top + b) ----
        __syncthreads();                       // all aggs reads done
        *(float4*)&aggs[r0 * AGP + c0t] = y0;  // stage y in aggs
        *(float4*)&aggs[r1 * AGP + c0t] = y1;
        __syncthreads();

        const int c2e = (tid & 31) * 4;        // 0..124 (128 out cols)
        const int nn0 = (tid >> 5) * 4;        // 4 nodes/thread
        const bool isM = (c2e < 64);
        const float* Wn = isM ? MwN : UwN;
        const float* bn = isM ? MbN : UbN;
        const int cc = isM ? c2e : c2e - 64;
        const float4 bv = *(const float4*)&bn[cc];

        #pragma unroll 1
        for (int h = 0; h < 2; h++) {          // two 2-node passes (reg cap)
            const int na = nn0 + 2 * h, nb = na + 1;
            float4 p0 = bv, p1 = bv;
            #pragma unroll 4
            for (int k = 0; k < 64; k += 4) {
                const float4 w0 = *(const float4*)&Wn[(k + 0) * 64 + cc];
                const float4 w1 = *(const float4*)&Wn[(k + 1) * 64 + cc];
                const float4 w2 = *(const float4*)&Wn[(k + 2) * 64 + cc];
                const float4 w3 = *(const float4*)&Wn[(k + 3) * 64 + cc];
                const float4 x0 = *(const float4*)&aggs[na * AGP + k];
                const float4 x1 = *(const float4*)&aggs[nb * AGP + k];
                p0.x += x0.x * w0.x + x0.y * w1.x + x0.z * w2.x + x0.w * w3.x;
                p0.y += x0.x * w0.y + x0.y * w1.y + x0.z * w2.y + x0.w * w3.y;
                p0.z += x0.x * w0.z + x0.y * w1.z + x0.z * w2.z + x0.w * w3.z;
                p0.w += x0.x * w0.w + x0.y * w1.w + x0.z * w2.w + x0.w * w3.w;
                p1.x += x1.x * w0.x + x1.y * w1.x + x1.z * w2.x + x1.w * w3.x;
                p1.y += x1.x * w0.y + x1.y * w1.y + x1.z * w2.y + x1.w * w3.y;
                p1.z += x1.x * w0.z + x1.y * w1.z + x1.z * w2.z + x1.w * w3.z;
                p1.w += x1.x * w0.w + x1.y * w1.w + x1.z * w2.w + x1.w * w3.w;
            }
            if (nbase + na < N) {
                H4 o;
                o.a = __float22half2_rn(make_float2(p0.x, p0.y));
                o.b = __float22half2_rn(make_float2(p0.z, p0.w));
                if (isM) *(H4*)&PMo[(size_t)(nbase + na) * 64 + cc] = o;
                else     *(H4*)&Tho[(size_t)(nbase + na) * 64 + cc] = o;
            }
            if (nbase + nb < N) {
                H4 o;
                o.a = __float22half2_rn(make_float2(p1.x, p1.y));
                o.b = __float22half2_rn(make_float2(p1.z, p1.w));
                if (isM) *(H4*)&PMo[(size_t)(nbase + nb) * 64 + cc] = o;
                else     *(H4*)&Tho[(size_t)(nbase + nb) * 64 + cc] = o;
            }
        }
    }
}

// ===========================================================================
// pool_head: out[g] = (sum_{n in graph g} y[n]) . Ww + Wb  (sorted batch_idx)
// ===========================================================================
__global__ __launch_bounds__(256) void pool_head(
    const float* __restrict__ Y, const int* __restrict__ bidx,
    const float* __restrict__ Ww, const float* __restrict__ Wb,
    float* __restrict__ out, int N)
{
    const int g = blockIdx.x;
    int a = 0, b = N;
    while (a < b) { int m = (a + b) >> 1; if (bidx[m] < g) a = m + 1; else b = m; }
    const int lo = a;
    b = N;
    while (a < b) { int m = (a + b) >> 1; if (bidx[m] < g + 1) a = m + 1; else b = m; }
    const int hi = a;

    const int tid = threadIdx.x;
    const int c4 = tid & 15, nl = tid >> 4;
    float4 s = make_float4(0.f, 0.f, 0.f, 0.f);
    for (int n = lo + nl; n < hi; n += 16) {
        const float4 v = *(const float4*)&Y[(size_t)n * HID + c4 * 4];
        s.x += v.x; s.y += v.y; s.z += v.z; s.w += v.w;
    }
    __shared__ float red[16 * 68];
    *(float4*)&red[nl * 68 + c4 * 4] = s;
    __syncthreads();
    if (tid < 64) {
        float t = 0.f;
        #pragma unroll
        for (int r = 0; r < 16; r++) t += red[r * 68 + tid];
        t *= Ww[tid];
        #pragma unroll
        for (int off = 32; off; off >>= 1) t += __shfl_down(t, off);
        if (tid == 0) out[g] = t + Wb[0];
    }
}

extern "C" void kernel_launch(void* const* d_in, const int* in_sizes, int n_in,
                              void* d_out, int out_size, void* d_ws, size_t ws_size,
                              hipStream_t stream) {
    const float* H    = (const float*)d_in[0];
    const float* Xe   = (const float*)d_in[1];
    const int*   ids  = (const int*)d_in[2];
    const int*   bidx = (const int*)d_in[3];
    const float* Mw0  = (const float*)d_in[4];
    const float* Mb0  = (const float*)d_in[5];
    const float* Uw0  = (const float*)d_in[6];
    const float* Ub0  = (const float*)d_in[7];
    const float* MwH  = (const float*)d_in[8];   // [3, 80, 64]
    const float* MbH  = (const float*)d_in[9];
    const float* UwH  = (const float*)d_in[10];  // [3, 128, 64]
    const float* UbH  = (const float*)d_in[11];
    const float* Ww   = (const float*)d_in[12];
    const float* Wb   = (const float*)d_in[13];
    float* out = (float*)d_out;

    const int N = in_sizes[0] / 32;
    const int E = in_sizes[1] / 16;
    const int* src = ids;
    const int* dst = ids + E;

    // ---- workspace (same total footprint as baseline):
    // bufA: PMa,Tha (N*256B) | bufB: PMb,Thb (N*256B) | Xes E*32B | pks E*4B
    // | rowptr | deg | bsums.  Final-layer f32 y overwrites bufA.
    __half* PMa  = (__half*)d_ws;                       // N*64 h
    __half* Tha  = PMa + (size_t)N * HID;               // N*64 h
    __half* PMb  = Tha + (size_t)N * HID;               // N*64 h
    __half* Thb  = PMb + (size_t)N * HID;               // N*64 h
    float*  yfin = (float*)d_ws;                        // N*64 f32 (= PMa+Tha)
    __half* Xes  = Thb + (size_t)N * HID;               // E*16 h
    unsigned* pks = (unsigned*)(Xes + (size_t)E * 16);  // E u32
    int* rowptr  = (int*)(pks + E);                     // N+1
    int* deg     = rowptr + (N + 1);                    // N
    int* bsums   = deg + N;                             // <=4096

    const int NB = (N + 2047) / 2048;
    const int eblocks = (E + 255) / 256;
    const int ntile   = (N + 31) / 32;

    // ---- CSR build + fp16 edge reorder ----
    hipMemsetAsync(deg, 0, (size_t)N * sizeof(int), stream);
    deg_count<<<eblocks, 256, 0, stream>>>(dst, deg, E);
    scan1<<<NB, 256, 0, stream>>>(deg, rowptr, bsums, N);
    scan2<<<1, 64, 0, stream>>>(bsums, NB);
    scan3<<<(N + 255) / 256, 256, 0, stream>>>(rowptr, bsums, N, E);
    hipMemsetAsync(deg, 0, (size_t)N * sizeof(int), stream);
    permute_k<<<eblocks, 256, 0, stream>>>(src, dst, rowptr, deg,
                                           Xe, Xes, pks, E);

    const float* MwH0 = MwH;                 const float* UwH0 = UwH;
    const float* MwH1 = MwH + 80 * HID;      const float* UwH1 = UwH + 128 * HID;
    const float* MwH2 = MwH + 2 * 80 * HID;  const float* UwH2 = UwH + 2 * 128 * HID;

    // ---- layer 0 (K1=32): pm from H, edge+fused-pm(next=H1 tops) ----
    pm_dual<32><<<ntile, 256, 0, stream>>>(H, Mw0, Mb0, Uw0, Ub0, PMa, Tha, N);
    edge_fused<true><<<ntile, 256, 0, stream>>>(
        PMa, Tha, Xes, pks, rowptr,
        Mw0 + 32 * HID, Uw0 + 32 * HID,
        MwH0, MbH, UwH0, UbH,
        PMb, Thb, nullptr, N);

    // ---- hidden layer 1: read B, fuse pm(next=H2 tops) -> A ----
    edge_fused<true><<<ntile, 256, 0, stream>>>(
        PMb, Thb, Xes, pks, rowptr,
        MwH0 + 64 * HID, UwH0 + 64 * HID,
        MwH1, MbH + HID, UwH1, UbH + HID,
        PMa, Tha, nullptr, N);

    // ---- hidden layer 2: read A, fuse pm(next=H3 tops) -> B ----
    edge_fused<true><<<ntile, 256, 0, stream>>>(
        PMa, Tha, Xes, pks, rowptr,
        MwH1 + 64 * HID, UwH1 + 64 * HID,
        MwH2, MbH + 2 * HID, UwH2, UbH + 2 * HID,
        PMb, Thb, nullptr, N);

    // ---- hidden layer 3 (last): read B, write f32 y into bufA ----
    edge_fused<false><<<ntile, 256, 0, stream>>>(
        PMb, Thb, Xes, pks, rowptr,
        MwH2 + 64 * HID, UwH2 + 64 * HID,
        nullptr, nullptr, nullptr, nullptr,
        nullptr, nullptr, yfin, N);

    // ---- pooling + head ----
    pool_head<<<256, 256, 0, stream>>>(yfin, bidx, Ww, Wb, out, N);
}